// Round 4
// baseline (781.905 us; speedup 1.0000x reference)
//
#include <hip/hip_runtime.h>
#include <stdint.h>

// NCA: B=8, C=16, H=W=128, hidden=128, 8 steps.
// ws layout: [0,8MB) mid, [8MB,16MB) cur, [16MB,+128KB) pre,
//            [+2MB) packed threefry mask bits, [+32KB) wpack. ~18.5 MB.

#define BATCH 8
#define CH 16
#define HT 128
#define WD 128
#define HIDN 128
#define PLANE (HT*WD)
#define IMG (CH*PLANE)
#define NELEM (BATCH*IMG)
#define NPIX (BATCH*PLANE)
#define WORDS_PER_STEP (NELEM/32)
#define NSTEPS 8

struct Keys { unsigned k[2*NSTEPS]; };

__host__ __device__ __forceinline__ unsigned rotl32u(unsigned v, int r) {
  return (v << r) | (v >> (32 - r));
}

// JAX threefry2x32 (20 rounds).
__host__ __device__ __forceinline__ void tf2x32(unsigned k0, unsigned k1,
                                                unsigned c0, unsigned c1,
                                                unsigned &o0, unsigned &o1) {
  const unsigned ks2 = k0 ^ k1 ^ 0x1BD11BDAu;
  unsigned x0 = c0 + k0, x1 = c1 + k1;
  x0 += x1; x1 = rotl32u(x1, 13); x1 ^= x0;
  x0 += x1; x1 = rotl32u(x1, 15); x1 ^= x0;
  x0 += x1; x1 = rotl32u(x1, 26); x1 ^= x0;
  x0 += x1; x1 = rotl32u(x1,  6); x1 ^= x0;
  x0 += k1; x1 += ks2 + 1u;
  x0 += x1; x1 = rotl32u(x1, 17); x1 ^= x0;
  x0 += x1; x1 = rotl32u(x1, 29); x1 ^= x0;
  x0 += x1; x1 = rotl32u(x1, 16); x1 ^= x0;
  x0 += x1; x1 = rotl32u(x1, 24); x1 ^= x0;
  x0 += ks2; x1 += k0 + 2u;
  x0 += x1; x1 = rotl32u(x1, 13); x1 ^= x0;
  x0 += x1; x1 = rotl32u(x1, 15); x1 ^= x0;
  x0 += x1; x1 = rotl32u(x1, 26); x1 ^= x0;
  x0 += x1; x1 = rotl32u(x1,  6); x1 ^= x0;
  x0 += k0; x1 += k1 + 3u;
  x0 += x1; x1 = rotl32u(x1, 17); x1 ^= x0;
  x0 += x1; x1 = rotl32u(x1, 29); x1 ^= x0;
  x0 += x1; x1 = rotl32u(x1, 16); x1 ^= x0;
  x0 += x1; x1 = rotl32u(x1, 24); x1 ^= x0;
  x0 += k1; x1 += ks2 + 4u;
  x0 += x1; x1 = rotl32u(x1, 13); x1 ^= x0;
  x0 += x1; x1 = rotl32u(x1, 15); x1 ^= x0;
  x0 += x1; x1 = rotl32u(x1, 26); x1 ^= x0;
  x0 += x1; x1 = rotl32u(x1,  6); x1 ^= x0;
  x0 += ks2; x1 += k0 + 5u;
  o0 = x0; o1 = x1;
}

__global__ __launch_bounds__(256) void mask_kernel(unsigned* __restrict__ mask,
                                                   Keys keys) {
  unsigned t = blockIdx.x * 256u + threadIdx.x;
  unsigned step = t >> 16;
  unsigned k0 = keys.k[2*step], k1 = keys.k[2*step + 1];
  unsigned base = (t & 65535u) << 5;
  unsigned word = 0u;
  #pragma unroll 4
  for (int i = 0; i < 32; ++i) {
    unsigned b1x, b2x;
    tf2x32(k0, k1, 0u, base + (unsigned)i, b1x, b2x);
    unsigned bits = b1x ^ b2x;
    word |= (((bits >> 9) != 0u) ? 1u : 0u) << i;
  }
  mask[t] = word;
}

// wpack[h][0..47] = w1[h][:], wpack[h][48..63] = w2[:][h]. 256B/row ->
// pure sequential s_load_dwordx16 stream per hidden unit.
__global__ __launch_bounds__(256) void wpack_kernel(
    const float* __restrict__ w1, const float* __restrict__ w2,
    float* __restrict__ wpack) {
  int t = blockIdx.x * 256 + threadIdx.x;   // 8192
  int h = t >> 6, j = t & 63;
  wpack[t] = (j < 48) ? w1[h * 48 + j] : w2[(j - 48) * HIDN + h];
}

// Step kernel A. 512 threads = 256 pixels (32x8) x 2 hidden-halves.
// Weights via wave-uniform s_load (scalar cache broadcast is free — r3's
// LDS broadcast cost 1KB/instr of LDS BW = 55us/step, the round-3 wall).
// amdgpu_waves_per_eu(4,4) pins the allocator's occupancy target: 128 VGPR
// budget, stops the spill-to-chase-8-waves behavior seen in r1-r3.
__global__ __launch_bounds__(512)
__attribute__((amdgpu_waves_per_eu(4, 4)))
void step_a(
    const float* __restrict__ s,
    const float* __restrict__ wpack,  // [128][64]
    const float* __restrict__ b1,     // [128]
    const float* __restrict__ b2,     // [16]
    const unsigned* __restrict__ mask,
    float* __restrict__ mid,
    unsigned char* __restrict__ pre) {
  __shared__ float red[256][17];      // dx-partial combine, padded

  const int tid = threadIdx.x;
  const int pix = tid & 255;
  const int half = __builtin_amdgcn_readfirstlane(tid >> 8);  // wave-uniform
  const int tileX = blockIdx.x, tileY = blockIdx.y, b = blockIdx.z;
  const int tx = pix & 31, ty = pix >> 5;
  const int gx = tileX * 32 + tx, gy = tileY * 8 + ty;

  // ---- perceive: direct global 3x3 (predicated borders) ----
  const float* sb = s + b * IMG;
  const int ctr = gy * WD + gx;
  bool yu = (gy > 0), yd = (gy < HT - 1), xl = (gx > 0), xr = (gx < WD - 1);

  float p[48];
  float premax;
  #pragma unroll
  for (int c = 0; c < CH; ++c) {
    const float* sc = sb + c * PLANE + ctr;
    float a11 = sc[0];
    float a00 = (yu && xl) ? sc[-WD - 1] : 0.f;
    float a01 = yu         ? sc[-WD]     : 0.f;
    float a02 = (yu && xr) ? sc[-WD + 1] : 0.f;
    float a10 = xl         ? sc[-1]      : 0.f;
    float a12 = xr         ? sc[1]       : 0.f;
    float a20 = (yd && xl) ? sc[WD - 1]  : 0.f;
    float a21 = yd         ? sc[WD]      : 0.f;
    float a22 = (yd && xr) ? sc[WD + 1]  : 0.f;
    p[c]      = a11;
    p[16 + c] = (a02 - a00) + 2.f * (a12 - a10) + (a22 - a20);
    p[32 + c] = (a20 - a00) + 2.f * (a21 - a01) + (a22 - a02);
    if (c == 3) {
      float m0 = fmaxf(fmaxf(a00, a01), fmaxf(a02, a10));
      float m1 = fmaxf(fmaxf(a11, a12), fmaxf(a20, a21));
      premax = fmaxf(fmaxf(m0, m1), a22);
    }
  }

  // ---- MLP over this thread's 64 hidden units (weights via s_load) ----
  float dx[16];
  #pragma unroll
  for (int o = 0; o < 16; ++o) dx[o] = 0.f;

  const float* wbase = wpack + half * 64 * 64;
  const float* b1base = b1 + half * 64;
  for (int i = 0; i < 64; ++i) {     // no unroll: 64 weight SGPRs/iter max
    const float* wr = wbase + i * 64;   // wave-uniform -> s_load_dwordx16
    float t0 = 0.f, t1 = 0.f, t2 = 0.f, t3 = 0.f;
    #pragma unroll
    for (int c = 0; c < 48; c += 4) {
      t0 = fmaf(p[c + 0], wr[c + 0], t0);
      t1 = fmaf(p[c + 1], wr[c + 1], t1);
      t2 = fmaf(p[c + 2], wr[c + 2], t2);
      t3 = fmaf(p[c + 3], wr[c + 3], t3);
    }
    float h = ((t0 + t1) + (t2 + t3)) + b1base[i];
    h = fmaxf(h, 0.f);
    #pragma unroll
    for (int o = 0; o < 16; ++o)
      dx[o] = fmaf(h, wr[48 + o], dx[o]);
  }

  // ---- combine halves, residual, masks ----
  if (half == 0) {
    #pragma unroll
    for (int o = 0; o < 16; ++o) red[pix][o] = dx[o];
  }
  __syncthreads();
  if (half == 0) {
    pre[b * PLANE + gy * WD + gx] = (premax > 0.1f) ? 1 : 0;
  } else {
    #pragma unroll
    for (int o = 0; o < 16; ++o) {
      float d = dx[o] + red[pix][o] + b2[o];
      d = fminf(fmaxf(d, -5.f), 5.f);
      unsigned mw = mask[((b * 16 + o) * HT + gy) * 4 + tileX];
      float v = p[o] + (((mw >> tx) & 1u) ? d : 0.f);
      mid[b * IMG + o * PLANE + gy * WD + gx] = v;
    }
  }
}

// Step kernel B: post-alive maxpool + apply pre&post, float4-vectorized.
__global__ __launch_bounds__(256) void step_b(
    const float* __restrict__ mid,
    const unsigned char* __restrict__ pre,
    float* __restrict__ out) {
  int t = blockIdx.x * 256 + threadIdx.x;   // NPIX/4 threads
  int b = t >> 12;
  int r = t & 4095;
  int y = r >> 5;
  int x0 = (r & 31) * 4;
  const float* m3 = mid + b * IMG + 3 * PLANE;

  float col[6];
  #pragma unroll
  for (int j = 0; j < 6; ++j) {
    int xx = x0 - 1 + j;
    float m = -1e30f;
    if ((unsigned)xx < WD) {
      #pragma unroll
      for (int dy = -1; dy <= 1; ++dy) {
        int yy = y + dy;
        if ((unsigned)yy < HT) m = fmaxf(m, m3[yy * WD + xx]);
      }
    }
    col[j] = m;
  }

  const unsigned char* pr = pre + b * PLANE + y * WD + x0;
  float f[4];
  #pragma unroll
  for (int i = 0; i < 4; ++i) {
    float mx = fmaxf(fmaxf(col[i], col[i + 1]), col[i + 2]);
    f[i] = ((mx > 0.1f) && pr[i]) ? 1.f : 0.f;
  }

  #pragma unroll
  for (int c = 0; c < CH; ++c) {
    const float4 v = *(const float4*)&mid[b * IMG + c * PLANE + y * WD + x0];
    float4 w;
    w.x = v.x * f[0]; w.y = v.y * f[1]; w.z = v.z * f[2]; w.w = v.w * f[3];
    *(float4*)&out[b * IMG + c * PLANE + y * WD + x0] = w;
  }
}

extern "C" void kernel_launch(void* const* d_in, const int* in_sizes, int n_in,
                              void* d_out, int out_size, void* d_ws, size_t ws_size,
                              hipStream_t stream) {
  const float* x  = (const float*)d_in[0];
  const float* w1 = (const float*)d_in[1];
  const float* b1 = (const float*)d_in[2];
  const float* w2 = (const float*)d_in[3];
  const float* b2 = (const float*)d_in[4];
  float* out = (float*)d_out;

  char* ws = (char*)d_ws;
  float* mid = (float*)ws;
  float* cur = (float*)(ws + (size_t)NELEM * 4);
  unsigned char* pre = (unsigned char*)(ws + 2 * (size_t)NELEM * 4);
  unsigned* mask = (unsigned*)(ws + 2 * (size_t)NELEM * 4 + 256 * 1024);
  float* wpack = (float*)(ws + 2 * (size_t)NELEM * 4 + 256 * 1024
                             + (size_t)NSTEPS * WORDS_PER_STEP * 4);

  // keys = jax.random.split(key(42), 8): keys[j] = threefry2x32((0,42),(0,j))
  Keys keys;
  for (int j = 0; j < NSTEPS; ++j) {
    unsigned a, b;
    tf2x32(0u, 42u, 0u, (unsigned)j, a, b);
    keys.k[2 * j] = a; keys.k[2 * j + 1] = b;
  }

  mask_kernel<<<(NSTEPS * WORDS_PER_STEP) / 256, 256, 0, stream>>>(mask, keys);
  wpack_kernel<<<HIDN * 64 / 256, 256, 0, stream>>>(w1, w2, wpack);

  const float* src = x;
  for (int s = 0; s < NSTEPS; ++s) {
    step_a<<<dim3(WD / 32, HT / 8, BATCH), 512, 0, stream>>>(
        src, wpack, b1, b2, mask + s * WORDS_PER_STEP, mid, pre);
    float* dst = (s == NSTEPS - 1) ? out : cur;
    step_b<<<(NPIX / 4) / 256, 256, 0, stream>>>(mid, pre, dst);
    src = cur;
  }
}

// Round 5
// 504.156 us; speedup vs baseline: 1.5509x; 1.5509x over previous
//
#include <hip/hip_runtime.h>
#include <stdint.h>

// NCA: B=8, C=16, H=W=128, hidden=128, 8 steps.
// ws: [0,8MB) mid, [8MB,16MB) cur, [16MB,+128KB) pre, [+2MB) mask bits,
//     [+24KB) w1T, [+8KB) w2T. ~18.3 MB.

#define BATCH 8
#define CH 16
#define HT 128
#define WD 128
#define HIDN 128
#define PLANE (HT*WD)
#define IMG (CH*PLANE)
#define NELEM (BATCH*IMG)
#define NPIX (BATCH*PLANE)
#define WORDS_PER_STEP (NELEM/32)
#define NSTEPS 8
#define NPIXB 128    // pixels per step_a block (one image row)

struct Keys { unsigned k[2*NSTEPS]; };

__host__ __device__ __forceinline__ unsigned rotl32u(unsigned v, int r) {
  return (v << r) | (v >> (32 - r));
}

// JAX threefry2x32 (20 rounds).
__host__ __device__ __forceinline__ void tf2x32(unsigned k0, unsigned k1,
                                                unsigned c0, unsigned c1,
                                                unsigned &o0, unsigned &o1) {
  const unsigned ks2 = k0 ^ k1 ^ 0x1BD11BDAu;
  unsigned x0 = c0 + k0, x1 = c1 + k1;
  x0 += x1; x1 = rotl32u(x1, 13); x1 ^= x0;
  x0 += x1; x1 = rotl32u(x1, 15); x1 ^= x0;
  x0 += x1; x1 = rotl32u(x1, 26); x1 ^= x0;
  x0 += x1; x1 = rotl32u(x1,  6); x1 ^= x0;
  x0 += k1; x1 += ks2 + 1u;
  x0 += x1; x1 = rotl32u(x1, 17); x1 ^= x0;
  x0 += x1; x1 = rotl32u(x1, 29); x1 ^= x0;
  x0 += x1; x1 = rotl32u(x1, 16); x1 ^= x0;
  x0 += x1; x1 = rotl32u(x1, 24); x1 ^= x0;
  x0 += ks2; x1 += k0 + 2u;
  x0 += x1; x1 = rotl32u(x1, 13); x1 ^= x0;
  x0 += x1; x1 = rotl32u(x1, 15); x1 ^= x0;
  x0 += x1; x1 = rotl32u(x1, 26); x1 ^= x0;
  x0 += x1; x1 = rotl32u(x1,  6); x1 ^= x0;
  x0 += k0; x1 += k1 + 3u;
  x0 += x1; x1 = rotl32u(x1, 17); x1 ^= x0;
  x0 += x1; x1 = rotl32u(x1, 29); x1 ^= x0;
  x0 += x1; x1 = rotl32u(x1, 16); x1 ^= x0;
  x0 += x1; x1 = rotl32u(x1, 24); x1 ^= x0;
  x0 += k1; x1 += ks2 + 4u;
  x0 += x1; x1 = rotl32u(x1, 13); x1 ^= x0;
  x0 += x1; x1 = rotl32u(x1, 15); x1 ^= x0;
  x0 += x1; x1 = rotl32u(x1, 26); x1 ^= x0;
  x0 += x1; x1 = rotl32u(x1,  6); x1 ^= x0;
  x0 += ks2; x1 += k0 + 5u;
  o0 = x0; o1 = x1;
}

__global__ __launch_bounds__(256) void mask_kernel(unsigned* __restrict__ mask,
                                                   Keys keys) {
  unsigned t = blockIdx.x * 256u + threadIdx.x;
  unsigned step = t >> 16;
  unsigned k0 = keys.k[2*step], k1 = keys.k[2*step + 1];
  unsigned base = (t & 65535u) << 5;
  unsigned word = 0u;
  #pragma unroll 4
  for (int i = 0; i < 32; ++i) {
    unsigned b1x, b2x;
    tf2x32(k0, k1, 0u, base + (unsigned)i, b1x, b2x);
    unsigned bits = b1x ^ b2x;
    word |= (((bits >> 9) != 0u) ? 1u : 0u) << i;
  }
  mask[t] = word;
}

// w1T[c][h] = w1[h][c]  (6144 floats); w2T[h][o] = w2[o][h] (2048 floats).
// Inner loops then read 16 consecutive floats -> one s_load_dwordx16.
__global__ __launch_bounds__(256) void wpack_kernel(
    const float* __restrict__ w1, const float* __restrict__ w2,
    float* __restrict__ w1T, float* __restrict__ w2T) {
  int t = blockIdx.x * 256 + threadIdx.x;   // 8192
  if (t < 48 * HIDN) {
    int c = t >> 7, h = t & 127;
    w1T[t] = w1[h * 48 + c];
  } else {
    int i = t - 48 * HIDN;
    int h = i >> 4, o = i & 15;
    w2T[i] = w2[o * HIDN + h];
  }
}

// Step kernel A. 256 threads = 128 pixels (one row) x 2 hid-halves.
// p[48] lives in LDS (written once by perceive, streamed one scalar per
// 16 FMAs) so the register live set is t[16]+dx[16]+scalars ~= 45 VGPR —
// fits the allocator's 64-VGPR/8-wave target WITHOUT spilling (rounds 1-4:
// p[48] in registers => 26 floats spilled to scratch => L2-bound at 83us).
// Weights via wave-uniform s_load from transposed pack (scalar broadcast).
__global__ __launch_bounds__(256) void step_a(
    const float* __restrict__ s,
    const float* __restrict__ w1T,   // [48][128]
    const float* __restrict__ w2T,   // [128][16]
    const float* __restrict__ b1,    // [128]
    const float* __restrict__ b2,    // [16]
    const unsigned* __restrict__ mask,
    float* __restrict__ mid,
    unsigned char* __restrict__ pre) {
  __shared__ float plds[48][NPIXB];   // 24.0 KB
  __shared__ float red[NPIXB][17];    // 8.7 KB (padded)

  const int tid = threadIdx.x;
  const int pix = tid & 127;
  const int half = __builtin_amdgcn_readfirstlane(tid >> 7);  // wave-uniform
  const int pid = blockIdx.x * NPIXB + pix;
  const int b = pid >> 14;
  const int r = pid & 16383;
  const int y = r >> 7, x = r & 127;

  // ---- perceive: each half computes 8 channels into LDS ----
  const float* sb = s + b * IMG;
  const int ctr = y * WD + x;
  const bool yu = (y > 0), yd = (y < HT - 1), xl = (x > 0), xr = (x < WD - 1);
  float premax = -1e30f;
  #pragma unroll
  for (int cc = 0; cc < 8; ++cc) {
    const int c = half * 8 + cc;
    const float* sc = sb + c * PLANE + ctr;
    float a11 = sc[0];
    float a00 = (yu && xl) ? sc[-WD - 1] : 0.f;
    float a01 = yu         ? sc[-WD]     : 0.f;
    float a02 = (yu && xr) ? sc[-WD + 1] : 0.f;
    float a10 = xl         ? sc[-1]      : 0.f;
    float a12 = xr         ? sc[1]       : 0.f;
    float a20 = (yd && xl) ? sc[WD - 1]  : 0.f;
    float a21 = yd         ? sc[WD]      : 0.f;
    float a22 = (yd && xr) ? sc[WD + 1]  : 0.f;
    plds[c][pix]      = a11;
    plds[16 + c][pix] = (a02 - a00) + 2.f * (a12 - a10) + (a22 - a20);
    plds[32 + c][pix] = (a20 - a00) + 2.f * (a21 - a01) + (a22 - a02);
    if (half == 0 && cc == 3) {
      float m0 = fmaxf(fmaxf(a00, a01), fmaxf(a02, a10));
      float m1 = fmaxf(fmaxf(a11, a12), fmaxf(a20, a21));
      premax = fmaxf(fmaxf(m0, m1), a22);
    }
  }
  __syncthreads();

  // ---- MLP: this half's 4 hid-chunks of 16; p streamed from LDS ----
  float dx[16];
  #pragma unroll
  for (int o = 0; o < 16; ++o) dx[o] = 0.f;

  for (int chf = 0; chf < 4; ++chf) {
    const int chunk = half * 4 + chf;
    const float* b1c = b1 + chunk * 16;
    float t[16];
    #pragma unroll
    for (int j = 0; j < 16; ++j) t[j] = b1c[j];

    #pragma unroll 2
    for (int c = 0; c < 48; ++c) {
      float pc = plds[c][pix];                    // ds_read_b32, conflict-free
      const float* wr = w1T + c * HIDN + chunk * 16;   // s_load_dwordx16
      #pragma unroll
      for (int j = 0; j < 16; ++j) t[j] = fmaf(pc, wr[j], t[j]);
    }
    #pragma unroll
    for (int j = 0; j < 16; ++j) {
      float h = fmaxf(t[j], 0.f);
      const float* w2r = w2T + (chunk * 16 + j) * 16;  // s_load_dwordx16
      #pragma unroll
      for (int o = 0; o < 16; ++o) dx[o] = fmaf(h, w2r[o], dx[o]);
    }
  }

  // ---- combine halves, residual, masks ----
  if (half == 0) {
    #pragma unroll
    for (int o = 0; o < 16; ++o) red[pix][o] = dx[o];
  }
  __syncthreads();
  if (half == 0) {
    pre[pid] = (premax > 0.1f) ? 1 : 0;
  } else {
    #pragma unroll
    for (int o = 0; o < 16; ++o) {
      float d = dx[o] + red[pix][o] + b2[o];
      d = fminf(fmaxf(d, -5.f), 5.f);
      unsigned mw = mask[((b * 16 + o) * HT + y) * 4 + (x >> 5)];
      float v = plds[o][pix] + (((mw >> (x & 31)) & 1u) ? d : 0.f);
      mid[b * IMG + o * PLANE + r] = v;
    }
  }
}

// Step kernel B: post-alive maxpool + apply pre&post, float4-vectorized.
__global__ __launch_bounds__(256) void step_b(
    const float* __restrict__ mid,
    const unsigned char* __restrict__ pre,
    float* __restrict__ out) {
  int t = blockIdx.x * 256 + threadIdx.x;   // NPIX/4 threads
  int b = t >> 12;
  int r = t & 4095;
  int y = r >> 5;
  int x0 = (r & 31) * 4;
  const float* m3 = mid + b * IMG + 3 * PLANE;

  float col[6];
  #pragma unroll
  for (int j = 0; j < 6; ++j) {
    int xx = x0 - 1 + j;
    float m = -1e30f;
    if ((unsigned)xx < WD) {
      #pragma unroll
      for (int dy = -1; dy <= 1; ++dy) {
        int yy = y + dy;
        if ((unsigned)yy < HT) m = fmaxf(m, m3[yy * WD + xx]);
      }
    }
    col[j] = m;
  }

  const unsigned char* pr = pre + b * PLANE + y * WD + x0;
  float f[4];
  #pragma unroll
  for (int i = 0; i < 4; ++i) {
    float mx = fmaxf(fmaxf(col[i], col[i + 1]), col[i + 2]);
    f[i] = ((mx > 0.1f) && pr[i]) ? 1.f : 0.f;
  }

  #pragma unroll
  for (int c = 0; c < CH; ++c) {
    const float4 v = *(const float4*)&mid[b * IMG + c * PLANE + y * WD + x0];
    float4 w;
    w.x = v.x * f[0]; w.y = v.y * f[1]; w.z = v.z * f[2]; w.w = v.w * f[3];
    *(float4*)&out[b * IMG + c * PLANE + y * WD + x0] = w;
  }
}

extern "C" void kernel_launch(void* const* d_in, const int* in_sizes, int n_in,
                              void* d_out, int out_size, void* d_ws, size_t ws_size,
                              hipStream_t stream) {
  const float* x  = (const float*)d_in[0];
  const float* w1 = (const float*)d_in[1];
  const float* b1 = (const float*)d_in[2];
  const float* w2 = (const float*)d_in[3];
  const float* b2 = (const float*)d_in[4];
  float* out = (float*)d_out;

  char* ws = (char*)d_ws;
  float* mid = (float*)ws;
  float* cur = (float*)(ws + (size_t)NELEM * 4);
  unsigned char* pre = (unsigned char*)(ws + 2 * (size_t)NELEM * 4);
  unsigned* mask = (unsigned*)(ws + 2 * (size_t)NELEM * 4 + 256 * 1024);
  float* w1T = (float*)(ws + 2 * (size_t)NELEM * 4 + 256 * 1024
                           + (size_t)NSTEPS * WORDS_PER_STEP * 4);
  float* w2T = w1T + 48 * HIDN;

  // keys = jax.random.split(key(42), 8): keys[j] = threefry2x32((0,42),(0,j))
  Keys keys;
  for (int j = 0; j < NSTEPS; ++j) {
    unsigned a, b;
    tf2x32(0u, 42u, 0u, (unsigned)j, a, b);
    keys.k[2 * j] = a; keys.k[2 * j + 1] = b;
  }

  mask_kernel<<<(NSTEPS * WORDS_PER_STEP) / 256, 256, 0, stream>>>(mask, keys);
  wpack_kernel<<<(48 * HIDN + HIDN * 16) / 256, 256, 0, stream>>>(w1, w2, w1T, w2T);

  const float* src = x;
  for (int s = 0; s < NSTEPS; ++s) {
    step_a<<<NPIX / NPIXB, 256, 0, stream>>>(
        src, w1T, w2T, b1, b2, mask + s * WORDS_PER_STEP, mid, pre);
    float* dst = (s == NSTEPS - 1) ? out : cur;
    step_b<<<(NPIX / 4) / 256, 256, 0, stream>>>(mid, pre, dst);
    src = cur;
  }
}

// Round 6
// 421.649 us; speedup vs baseline: 1.8544x; 1.1957x over previous
//
#include <hip/hip_runtime.h>
#include <stdint.h>

// NCA: B=8, C=16, H=W=128, hidden=128, 8 steps.
// ws: [0,8MB) mid, [8MB,16MB) cur, [16MB,+128KB) pre, [+2MB) mask bits,
//     [+24KB) w1T, [+8KB) w2T. ~18.3 MB.

#define BATCH 8
#define CH 16
#define HT 128
#define WD 128
#define HIDN 128
#define PLANE (HT*WD)
#define IMG (CH*PLANE)
#define NELEM (BATCH*IMG)
#define NPIX (BATCH*PLANE)
#define WORDS_PER_STEP (NELEM/32)
#define NSTEPS 8
#define NPIXB 128    // pixels per step_a block (one image row)
#define PROW 52      // plds row stride (floats): 16B-aligned, conflict-free b128

struct Keys { unsigned k[2*NSTEPS]; };

__host__ __device__ __forceinline__ unsigned rotl32u(unsigned v, int r) {
  return (v << r) | (v >> (32 - r));
}

// JAX threefry2x32 (20 rounds).
__host__ __device__ __forceinline__ void tf2x32(unsigned k0, unsigned k1,
                                                unsigned c0, unsigned c1,
                                                unsigned &o0, unsigned &o1) {
  const unsigned ks2 = k0 ^ k1 ^ 0x1BD11BDAu;
  unsigned x0 = c0 + k0, x1 = c1 + k1;
  x0 += x1; x1 = rotl32u(x1, 13); x1 ^= x0;
  x0 += x1; x1 = rotl32u(x1, 15); x1 ^= x0;
  x0 += x1; x1 = rotl32u(x1, 26); x1 ^= x0;
  x0 += x1; x1 = rotl32u(x1,  6); x1 ^= x0;
  x0 += k1; x1 += ks2 + 1u;
  x0 += x1; x1 = rotl32u(x1, 17); x1 ^= x0;
  x0 += x1; x1 = rotl32u(x1, 29); x1 ^= x0;
  x0 += x1; x1 = rotl32u(x1, 16); x1 ^= x0;
  x0 += x1; x1 = rotl32u(x1, 24); x1 ^= x0;
  x0 += ks2; x1 += k0 + 2u;
  x0 += x1; x1 = rotl32u(x1, 13); x1 ^= x0;
  x0 += x1; x1 = rotl32u(x1, 15); x1 ^= x0;
  x0 += x1; x1 = rotl32u(x1, 26); x1 ^= x0;
  x0 += x1; x1 = rotl32u(x1,  6); x1 ^= x0;
  x0 += k0; x1 += k1 + 3u;
  x0 += x1; x1 = rotl32u(x1, 17); x1 ^= x0;
  x0 += x1; x1 = rotl32u(x1, 29); x1 ^= x0;
  x0 += x1; x1 = rotl32u(x1, 16); x1 ^= x0;
  x0 += x1; x1 = rotl32u(x1, 24); x1 ^= x0;
  x0 += k1; x1 += ks2 + 4u;
  x0 += x1; x1 = rotl32u(x1, 13); x1 ^= x0;
  x0 += x1; x1 = rotl32u(x1, 15); x1 ^= x0;
  x0 += x1; x1 = rotl32u(x1, 26); x1 ^= x0;
  x0 += x1; x1 = rotl32u(x1,  6); x1 ^= x0;
  x0 += ks2; x1 += k0 + 5u;
  o0 = x0; o1 = x1;
}

__global__ __launch_bounds__(256) void mask_kernel(unsigned* __restrict__ mask,
                                                   Keys keys) {
  unsigned t = blockIdx.x * 256u + threadIdx.x;
  unsigned step = t >> 16;
  unsigned k0 = keys.k[2*step], k1 = keys.k[2*step + 1];
  unsigned base = (t & 65535u) << 5;
  unsigned word = 0u;
  #pragma unroll 4
  for (int i = 0; i < 32; ++i) {
    unsigned b1x, b2x;
    tf2x32(k0, k1, 0u, base + (unsigned)i, b1x, b2x);
    unsigned bits = b1x ^ b2x;
    word |= (((bits >> 9) != 0u) ? 1u : 0u) << i;
  }
  mask[t] = word;
}

// w1T[c][h] = w1[h][c]; w2T[h][o] = w2[o][h].
__global__ __launch_bounds__(256) void wpack_kernel(
    const float* __restrict__ w1, const float* __restrict__ w2,
    float* __restrict__ w1T, float* __restrict__ w2T) {
  int t = blockIdx.x * 256 + threadIdx.x;   // 8192
  if (t < 48 * HIDN) {
    int c = t >> 7, h = t & 127;
    w1T[t] = w1[h * 48 + c];
  } else {
    int i = t - 48 * HIDN;
    int h = i >> 4, o = i & 15;
    w2T[i] = w2[o * HIDN + h];
  }
}

// Step kernel A. 256 threads = 128 pixels x 2 hid-halves.
// p transposed in LDS as plds[pix][52] -> ds_read_b128 (4 p's per read).
// Inner c-quad: 1 ds_read_b128 + 4 s_load_dwordx16 + 64 FMA => only 12
// ds-consumption points per chunk (r5 had 48 -> lgkmcnt(0) drained the
// prefetched s_load queue at each one; SMEM is out-of-order so mixed
// ds/smem forces full drains — this was the 61% VALU-idle).
// red[] aliased into dead plds columns 16..31 after the MLP loop.
__global__ __launch_bounds__(256) void step_a(
    const float* __restrict__ s,
    const float* __restrict__ w1T,   // [48][128]
    const float* __restrict__ w2T,   // [128][16]
    const float* __restrict__ b1,    // [128]
    const float* __restrict__ b2,    // [16]
    const unsigned* __restrict__ mask,
    float* __restrict__ mid,
    unsigned char* __restrict__ pre) {
  __shared__ float plds[NPIXB][PROW];   // 26.6 KB

  const int tid = threadIdx.x;
  const int pix = tid & 127;
  const int half = __builtin_amdgcn_readfirstlane(tid >> 7);  // wave-uniform
  const int pid = blockIdx.x * NPIXB + pix;
  const int b = pid >> 14;
  const int r = pid & 16383;
  const int y = r >> 7, x = r & 127;

  // ---- perceive: each half computes 8 channels into LDS ----
  const float* sb = s + b * IMG;
  const int ctr = y * WD + x;
  const bool yu = (y > 0), yd = (y < HT - 1), xl = (x > 0), xr = (x < WD - 1);
  float premax = -1e30f;
  #pragma unroll
  for (int cc = 0; cc < 8; ++cc) {
    const int c = half * 8 + cc;
    const float* sc = sb + c * PLANE + ctr;
    float a11 = sc[0];
    float a00 = (yu && xl) ? sc[-WD - 1] : 0.f;
    float a01 = yu         ? sc[-WD]     : 0.f;
    float a02 = (yu && xr) ? sc[-WD + 1] : 0.f;
    float a10 = xl         ? sc[-1]      : 0.f;
    float a12 = xr         ? sc[1]       : 0.f;
    float a20 = (yd && xl) ? sc[WD - 1]  : 0.f;
    float a21 = yd         ? sc[WD]      : 0.f;
    float a22 = (yd && xr) ? sc[WD + 1]  : 0.f;
    plds[pix][c]      = a11;
    plds[pix][16 + c] = (a02 - a00) + 2.f * (a12 - a10) + (a22 - a20);
    plds[pix][32 + c] = (a20 - a00) + 2.f * (a21 - a01) + (a22 - a02);
    if (half == 0 && cc == 3) {
      float m0 = fmaxf(fmaxf(a00, a01), fmaxf(a02, a10));
      float m1 = fmaxf(fmaxf(a11, a12), fmaxf(a20, a21));
      premax = fmaxf(fmaxf(m0, m1), a22);
    }
  }
  __syncthreads();

  // ---- MLP: this half's 4 hid-chunks of 16 ----
  float dx[16];
  #pragma unroll
  for (int o = 0; o < 16; ++o) dx[o] = 0.f;

  for (int chf = 0; chf < 4; ++chf) {
    const int chunk = half * 4 + chf;
    const float* b1c = b1 + chunk * 16;
    float t[16];
    #pragma unroll
    for (int j = 0; j < 16; ++j) t[j] = b1c[j];

    #pragma unroll 2
    for (int q = 0; q < 12; ++q) {
      const float4 pq = *(const float4*)&plds[pix][4 * q];  // ds_read_b128
      const float* wr0 = w1T + (4 * q) * HIDN + chunk * 16; // s_load_dwordx16 x4
      const float* wr1 = wr0 + HIDN;
      const float* wr2 = wr1 + HIDN;
      const float* wr3 = wr2 + HIDN;
      #pragma unroll
      for (int j = 0; j < 16; ++j) {
        float tj = t[j];
        tj = fmaf(pq.x, wr0[j], tj);
        tj = fmaf(pq.y, wr1[j], tj);
        tj = fmaf(pq.z, wr2[j], tj);
        tj = fmaf(pq.w, wr3[j], tj);
        t[j] = tj;
      }
    }
    #pragma unroll
    for (int j = 0; j < 16; ++j) {
      float h = fmaxf(t[j], 0.f);
      const float* w2r = w2T + (chunk * 16 + j) * 16;   // s_load_dwordx16
      #pragma unroll
      for (int o = 0; o < 16; ++o) dx[o] = fmaf(h, w2r[o], dx[o]);
    }
  }

  // ---- combine halves (red aliased into plds cols 16..31), residual ----
  __syncthreads();   // all plds reads of the MLP loop complete
  if (half == 0) {
    #pragma unroll
    for (int o = 0; o < 16; ++o) plds[pix][16 + o] = dx[o];
    pre[pid] = (premax > 0.1f) ? 1 : 0;
  }
  __syncthreads();
  if (half == 1) {
    #pragma unroll
    for (int o = 0; o < 16; ++o) {
      float d = dx[o] + plds[pix][16 + o] + b2[o];
      d = fminf(fmaxf(d, -5.f), 5.f);
      unsigned mw = mask[((b * 16 + o) * HT + y) * 4 + (x >> 5)];
      float v = plds[pix][o] + (((mw >> (x & 31)) & 1u) ? d : 0.f);
      mid[b * IMG + o * PLANE + r] = v;
    }
  }
}

// Step kernel B: post-alive maxpool + apply pre&post.
// 4-way channel-quarter split: 8192 waves (r5: 512 waves = 2/CU was
// latency-bound on the 16 independent float4 streams).
__global__ __launch_bounds__(256) void step_b(
    const float* __restrict__ mid,
    const unsigned char* __restrict__ pre,
    float* __restrict__ out) {
  int t = blockIdx.x * 256 + threadIdx.x;   // NPIX threads
  int cq = t >> 15;          // channel quarter 0..3
  int qid = t & 32767;       // pixel-quad id
  int b = qid >> 12;
  int r = qid & 4095;
  int y = r >> 5;
  int x0 = (r & 31) * 4;
  const float* m3 = mid + b * IMG + 3 * PLANE;

  float col[6];
  #pragma unroll
  for (int j = 0; j < 6; ++j) {
    int xx = x0 - 1 + j;
    float m = -1e30f;
    if ((unsigned)xx < WD) {
      #pragma unroll
      for (int dy = -1; dy <= 1; ++dy) {
        int yy = y + dy;
        if ((unsigned)yy < HT) m = fmaxf(m, m3[yy * WD + xx]);
      }
    }
    col[j] = m;
  }

  const unsigned char* pr = pre + b * PLANE + y * WD + x0;
  float f[4];
  #pragma unroll
  for (int i = 0; i < 4; ++i) {
    float mx = fmaxf(fmaxf(col[i], col[i + 1]), col[i + 2]);
    f[i] = ((mx > 0.1f) && pr[i]) ? 1.f : 0.f;
  }

  #pragma unroll
  for (int cc = 0; cc < 4; ++cc) {
    int c = cq * 4 + cc;
    const float4 v = *(const float4*)&mid[b * IMG + c * PLANE + y * WD + x0];
    float4 w;
    w.x = v.x * f[0]; w.y = v.y * f[1]; w.z = v.z * f[2]; w.w = v.w * f[3];
    *(float4*)&out[b * IMG + c * PLANE + y * WD + x0] = w;
  }
}

extern "C" void kernel_launch(void* const* d_in, const int* in_sizes, int n_in,
                              void* d_out, int out_size, void* d_ws, size_t ws_size,
                              hipStream_t stream) {
  const float* x  = (const float*)d_in[0];
  const float* w1 = (const float*)d_in[1];
  const float* b1 = (const float*)d_in[2];
  const float* w2 = (const float*)d_in[3];
  const float* b2 = (const float*)d_in[4];
  float* out = (float*)d_out;

  char* ws = (char*)d_ws;
  float* mid = (float*)ws;
  float* cur = (float*)(ws + (size_t)NELEM * 4);
  unsigned char* pre = (unsigned char*)(ws + 2 * (size_t)NELEM * 4);
  unsigned* mask = (unsigned*)(ws + 2 * (size_t)NELEM * 4 + 256 * 1024);
  float* w1T = (float*)(ws + 2 * (size_t)NELEM * 4 + 256 * 1024
                           + (size_t)NSTEPS * WORDS_PER_STEP * 4);
  float* w2T = w1T + 48 * HIDN;

  // keys = jax.random.split(key(42), 8): keys[j] = threefry2x32((0,42),(0,j))
  Keys keys;
  for (int j = 0; j < NSTEPS; ++j) {
    unsigned a, b;
    tf2x32(0u, 42u, 0u, (unsigned)j, a, b);
    keys.k[2 * j] = a; keys.k[2 * j + 1] = b;
  }

  mask_kernel<<<(NSTEPS * WORDS_PER_STEP) / 256, 256, 0, stream>>>(mask, keys);
  wpack_kernel<<<(48 * HIDN + HIDN * 16) / 256, 256, 0, stream>>>(w1, w2, w1T, w2T);

  const float* src = x;
  for (int s = 0; s < NSTEPS; ++s) {
    step_a<<<NPIX / NPIXB, 256, 0, stream>>>(
        src, w1T, w2T, b1, b2, mask + s * WORDS_PER_STEP, mid, pre);
    float* dst = (s == NSTEPS - 1) ? out : cur;
    step_b<<<NPIX / 256, 256, 0, stream>>>(mid, pre, dst);
    src = cur;
  }
}